// Round 1
// 1077.911 us; speedup vs baseline: 1.6442x; 1.6442x over previous
//
#include <hip/hip_runtime.h>

#define T_SEQ  2048
#define TK_SEQ 2049
#define JP     2080                       // padded key length (zeroed pads)
#define SCALE_F 0.08838834764831845f
#define SL_F    0.12751744f               // SCALE * log2(e)

typedef __attribute__((ext_vector_type(8))) short short8;
typedef __attribute__((ext_vector_type(4))) float f32x4;

__device__ __forceinline__ unsigned short f2bf(float f) {
  unsigned int u = __float_as_uint(f);
  u += 0x7fff + ((u >> 16) & 1);          // round-to-nearest-even
  return (unsigned short)(u >> 16);
}

// ---------------------------------------------------------------------------
// Naive tiled f32 GEMM: C[M,N] = A[M,K] * B[N,K]^T.  (unchanged this round)
// ---------------------------------------------------------------------------
__global__ __launch_bounds__(256) void ngemm_bt(const float* __restrict__ A,
                                                const float* __restrict__ B,
                                                float* __restrict__ C,
                                                int M, int N, int K) {
  __shared__ float As[64 * 17];
  __shared__ float Bs[64 * 17];
  const int tid = threadIdx.x;
  const int tx = tid & 15, ty = tid >> 4;
  const int m0 = blockIdx.y << 6;
  const int n0 = blockIdx.x << 6;

  float acc[4][4] = {};

  for (int k0 = 0; k0 < K; k0 += 16) {
    __syncthreads();
#pragma unroll
    for (int v = 0; v < 4; ++v) {
      int id = tid + (v << 8);
      int r = id >> 4, c = id & 15;
      As[r * 17 + c] = A[(size_t)(m0 + r) * K + k0 + c];
      Bs[r * 17 + c] = B[(size_t)(n0 + r) * K + k0 + c];
    }
    __syncthreads();
#pragma unroll
    for (int kk = 0; kk < 16; ++kk) {
      float a[4], b[4];
#pragma unroll
      for (int i = 0; i < 4; ++i) a[i] = As[(ty * 4 + i) * 17 + kk];
#pragma unroll
      for (int j = 0; j < 4; ++j) b[j] = Bs[(tx * 4 + j) * 17 + kk];
#pragma unroll
      for (int i = 0; i < 4; ++i)
#pragma unroll
        for (int j = 0; j < 4; ++j) acc[i][j] += a[i] * b[j];
    }
  }
#pragma unroll
  for (int i = 0; i < 4; ++i)
#pragma unroll
    for (int j = 0; j < 4; ++j)
      C[(size_t)(m0 + ty * 4 + i) * N + n0 + tx * 4 + j] = acc[i][j];
}

// ---------------------------------------------------------------------------
// RoPE + assemble bf16 operands for MFMA attention:
//   qb [t][h][d]      bf16 (2048 x 2048)
//   kb [j][g][d]      bf16 (2080 x 512), j=0 sink (not roped), j>2048 zero pad
//   vtb[g*128+d][j]   bf16 (512 x 2080) -- V TRANSPOSED, zero pad
// ---------------------------------------------------------------------------
__global__ void rope_prep_bf16(const float* __restrict__ qkv,
                               const float* __restrict__ cosb,
                               const float* __restrict__ sinb,
                               const float* __restrict__ ksink,
                               const float* __restrict__ vsink,
                               unsigned short* __restrict__ qb,
                               unsigned short* __restrict__ kb,
                               unsigned short* __restrict__ vtb) {
  const int NQ = T_SEQ * 2048;            // 4,194,304
  const int NK = JP * 512;                // 1,064,960
  int idx = blockIdx.x * 256 + threadIdx.x;
  if (idx < NQ) {
    int t = idx >> 11, rem = idx & 2047;
    int h = rem >> 7, d = rem & 127;
    int g = h >> 2, qi = h & 3;
    const float* src = qkv + (size_t)t * 3072 + g * 768 + qi * 128;
    float val;
    if (d < 64) {
      val = src[d] * cosb[t * 64 + d] - src[d + 64] * sinb[t * 64 + d];
    } else {
      int dd = d - 64;
      val = src[dd] * sinb[t * 64 + dd] + src[d] * cosb[t * 64 + dd];
    }
    qb[idx] = f2bf(val);
  } else if (idx < NQ + NK) {
    int r = idx - NQ;
    int j = r >> 9, rem = r & 511;
    int g = rem >> 7, d = rem & 127;
    float val;
    if (j == 0) {
      val = ksink[(g << 7) + d];
    } else if (j <= T_SEQ) {
      int t = j - 1;
      const float* src = qkv + (size_t)t * 3072 + g * 768 + 512;
      if (d < 64) {
        val = src[d] * cosb[t * 64 + d] - src[d + 64] * sinb[t * 64 + d];
      } else {
        int dd = d - 64;
        val = src[dd] * sinb[t * 64 + dd] + src[d] * cosb[t * 64 + dd];
      }
    } else {
      val = 0.f;                          // zero pad: MFMA-safe
    }
    kb[r] = f2bf(val);
  } else {
    int r = idx - NQ - NK;
    int j = r >> 9, rem = r & 511;
    int g = rem >> 7, d = rem & 127;
    float val;
    if (j == 0)            val = vsink[(g << 7) + d];
    else if (j <= T_SEQ)   val = qkv[(size_t)(j - 1) * 3072 + g * 768 + 640 + d];
    else                   val = 0.f;
    vtb[(size_t)(g * 128 + d) * JP + j] = f2bf(val);
  }
}

// ---------------------------------------------------------------------------
// MFMA flash attention (bf16 in, f32 accum).
// Block = 4 waves = 4 heads of one group; wave owns a 16-query tile x 1 head.
// Per 32-key chunk:  S^T = mfma(K, Q^T)  [8 mfma], online softmax in-register,
//                    O^T += mfma(V^T, P^T) [8 mfma].
// K-row permutation (row m <-> j = 8*(m>>2)+(m&3), tile1 +4) makes the S^T
// output registers land exactly in the PV B-fragment layout: no cross-lane
// exchange for the P transpose.
// ---------------------------------------------------------------------------
__global__ __launch_bounds__(256) void attn_mfma_bf16(const unsigned short* __restrict__ qb,
                                                      const unsigned short* __restrict__ kb,
                                                      const unsigned short* __restrict__ vtb,
                                                      float* __restrict__ of) {
  const int bid  = blockIdx.x;
  const int tile = bid >> 2;
  const int g    = bid & 3;
  const int wv   = threadIdx.x >> 6;      // head within group
  const int h    = g * 4 + wv;
  const int lane = threadIdx.x & 63;
  const int lo   = lane & 15;
  const int hi   = lane >> 4;
  const int t0   = tile << 4;
  const int t    = t0 + lo;               // this lane's q row

  // Q fragment (B operand of QK): lane holds q[t][d0*32 + 8*hi + e]
  short8 qfrag[4];
  {
    const unsigned short* qp = qb + (size_t)t * 2048 + h * 128 + (hi << 3);
#pragma unroll
    for (int d0 = 0; d0 < 4; ++d0) qfrag[d0] = *(const short8*)(qp + d0 * 32);
  }

  f32x4 acc[8];
  const f32x4 z4 = {0.f, 0.f, 0.f, 0.f};
#pragma unroll
  for (int dt = 0; dt < 8; ++dt) acc[dt] = z4;

  float m = -1e4f, l = 0.f;               // m floor > -1e30 sentinel (log2 dom.)

  int jlo = t0 - 1022; if (jlo < 0) jlo = 0;
  const int jb0  = jlo & ~31;
  const int jmax = t0 + 16;               // largest valid j = (t0+15)+1
  const int jrowA = ((lo >> 2) << 3) + (lo & 3);   // permuted A-row -> j offset

  for (int jb = jb0; jb <= jmax; jb += 32) {
    // ---- QK^T: two 16x16 S^T tiles over K=128 (4 d-chunks)
    const unsigned short* kbase = kb + (size_t)(jb + jrowA) * 512 + g * 128 + (hi << 3);
    f32x4 sa = z4, sb = z4;
#pragma unroll
    for (int d0 = 0; d0 < 4; ++d0) {
      short8 ka = *(const short8*)(kbase + d0 * 32);
      short8 kB = *(const short8*)(kbase + 4 * 512 + d0 * 32);
      sa = __builtin_amdgcn_mfma_f32_16x16x32_bf16(ka, qfrag[d0], sa, 0, 0, 0);
      sb = __builtin_amdgcn_mfma_f32_16x16x32_bf16(kB, qfrag[d0], sb, 0, 0, 0);
    }

    // lane holds scores for q=t, j = jb + 8*hi + r  (r<4: sa, r>=4: sb)
    float z[8];
    const int jbase = jb + (hi << 3);
    const bool interior = (jb >= t0 - 1007) && (jb <= t0 - 30);
    if (interior) {
#pragma unroll
      for (int r = 0; r < 4; ++r) { z[r] = sa[r] * SL_F; z[r + 4] = sb[r] * SL_F; }
    } else {
#pragma unroll
      for (int r = 0; r < 8; ++r) {
        float sv = (r < 4) ? sa[r] : sb[r - 4];
        int j = jbase + r;
        bool valid = (j <= t + 1) && (j >= t - 1022);
        z[r] = valid ? sv * SL_F : -1e30f;
      }
    }

    // online softmax (log2 domain); stats replicated across the 4 hi-lanes of q
    float cm = z[0];
#pragma unroll
    for (int r = 1; r < 8; ++r) cm = fmaxf(cm, z[r]);
    cm = fmaxf(cm, __shfl_xor(cm, 16, 64));
    cm = fmaxf(cm, __shfl_xor(cm, 32, 64));
    float mn = fmaxf(m, cm);
    float a = exp2f(m - mn);
    float p[8], ls = 0.f;
#pragma unroll
    for (int r = 0; r < 8; ++r) { p[r] = exp2f(z[r] - mn); ls += p[r]; }
    ls += __shfl_xor(ls, 16, 64);
    ls += __shfl_xor(ls, 32, 64);
    l = l * a + ls;
    m = mn;
#pragma unroll
    for (int dt = 0; dt < 8; ++dt) acc[dt] *= a;

    // pack P -> bf16 B-fragment: element e <-> j = jbase + e  (pure local)
    short8 pfrag;
#pragma unroll
    for (int e = 0; e < 8; ++e) pfrag[e] = (short)f2bf(p[e]);

    // ---- PV: O^T += V^T * P^T  (8 d-tiles of 16)
    const unsigned short* vbase = vtb + (size_t)(g * 128 + lo) * JP + jb + (hi << 3);
#pragma unroll
    for (int dt = 0; dt < 8; ++dt) {
      short8 vf = *(const short8*)(vbase + (size_t)dt * 16 * JP);
      acc[dt] = __builtin_amdgcn_mfma_f32_16x16x32_bf16(vf, pfrag, acc[dt], 0, 0, 0);
    }
  }

  // epilogue: acc[dt][r] = O^T[16*dt + 4*hi + r][q=lo]
  const float inv = 1.f / l;
  float* op = of + (size_t)t * 2048 + h * 128 + (hi << 2);
#pragma unroll
  for (int dt = 0; dt < 8; ++dt) {
    f32x4 o4 = acc[dt] * inv;
    *(f32x4*)(op + dt * 16) = o4;
  }
}

extern "C" void kernel_launch(void* const* d_in, const int* in_sizes, int n_in,
                              void* d_out, int out_size, void* d_ws, size_t ws_size,
                              hipStream_t stream) {
  const float* x     = (const float*)d_in[0];   // (2048, 2048) f32
  const float* cosb  = (const float*)d_in[1];   // (2048, 64)   f32
  const float* sinb  = (const float*)d_in[2];   // (2048, 64)   f32
  const float* Wa    = (const float*)d_in[3];   // (3072, 2048) f32
  const float* Wp    = (const float*)d_in[4];   // (2048, 2048) f32
  const float* ksink = (const float*)d_in[5];   // (512,)       f32
  const float* vsink = (const float*)d_in[6];   // (512,)       f32
  float* y = (float*)d_out;                     // (2048, 2048) f32

  char* ws = (char*)d_ws;
  float*          qkv = (float*)ws;                         // 25,165,824 B
  unsigned short* qb  = (unsigned short*)(ws + 25165824);   //  8,388,608 B
  unsigned short* kbb = (unsigned short*)(ws + 33554432);   //  2,129,920 B
  unsigned short* vtb = (unsigned short*)(ws + 35684352);   //  2,129,920 B
  float*          of  = (float*)(ws + 37814272);            // 16,777,216 B -> 54,591,488 total

  // 1. qkv = x @ W_attn^T  (f32)
  ngemm_bt<<<dim3(48, 32), 256, 0, stream>>>(x, Wa, qkv, 2048, 3072, 2048);
  // 2. RoPE + bf16 operand assembly (q, k, V^T; zero-padded to JP)
  rope_prep_bf16<<<24704, 256, 0, stream>>>(qkv, cosb, sinb, ksink, vsink, qb, kbb, vtb);
  // 3. MFMA flash attention
  attn_mfma_bf16<<<512, 256, 0, stream>>>(qb, kbb, vtb, of);
  // 4. y = o @ W_proj^T  (f32)
  ngemm_bt<<<dim3(32, 32), 256, 0, stream>>>(of, Wp, y, 2048, 2048, 2048);
}

// Round 2
// 401.596 us; speedup vs baseline: 4.4131x; 2.6841x over previous
//
#include <hip/hip_runtime.h>

#define T_SEQ  2048
#define TK_SEQ 2049
#define JP     2080                       // padded key length (zeroed pads)
#define SCALE_F 0.08838834764831845f
#define SL_F    0.12751744f               // SCALE * log2(e)

typedef __attribute__((ext_vector_type(8))) short short8;
typedef __attribute__((ext_vector_type(4))) float f32x4;

__device__ __forceinline__ unsigned short f2bf(float f) {
  unsigned int u = __float_as_uint(f);
  u += 0x7fff + ((u >> 16) & 1);          // round-to-nearest-even
  return (unsigned short)(u >> 16);
}

// ---------------------------------------------------------------------------
// Split-f32 MFMA GEMM: C[M,N] = A[M,K] * B[N,K]^T, f32 in/out.
// Each f32 is split during staging into hi=trunc_bf16(x), lo=bf16(x-hi);
// C ~= Ah*Bh + Ah*Bl + Al*Bh  (f32 accum; dropped Al*Bl ~ 2^-14 relative).
// 128x128 tile, 4 waves (2x2), 4x4 frags of mfma_f32_16x16x32_bf16, BK=32.
// LDS row stride 56 bf16 = 112 B: 16B-aligned b128 reads, 28-bank stride
// -> 2 lanes/bank (conflict-free per m136).
// ---------------------------------------------------------------------------
#define LDK 56

__global__ __launch_bounds__(256, 2) void gemm_bt_split(const float* __restrict__ A,
                                                        const float* __restrict__ B,
                                                        float* __restrict__ C,
                                                        int M, int N, int K) {
  __shared__ unsigned short Ah[128 * LDK], Al[128 * LDK];
  __shared__ unsigned short Bh[128 * LDK], Bl[128 * LDK];

  const int tid  = threadIdx.x;
  const int lane = tid & 63;
  const int wid  = tid >> 6;
  const int wm   = (wid >> 1) << 6;       // wave row offset: 0 / 64
  const int wn   = (wid & 1) << 6;        // wave col offset: 0 / 64
  const int lo16 = lane & 15;
  const int hi4  = lane >> 4;
  const int m0   = blockIdx.y << 7;
  const int n0   = blockIdx.x << 7;

  // staging map: id = v*256 + tid; row = id>>3 (0..127); kc = (id&7)*4
  const float* pa[4];
  const float* pb[4];
  int wofs[4];
#pragma unroll
  for (int v = 0; v < 4; ++v) {
    int id = (v << 8) + tid;
    int r  = id >> 3;
    int kc = (id & 7) << 2;
    pa[v]   = A + (size_t)(m0 + r) * K + kc;
    pb[v]   = B + (size_t)(n0 + r) * K + kc;
    wofs[v] = r * LDK + kc;
  }

  // ds_read offsets (frag layout: row = lane&15, k = (lane>>4)*8 + e)
  int ra[4], rb[4];
#pragma unroll
  for (int i = 0; i < 4; ++i) {
    ra[i] = (wm + i * 16 + lo16) * LDK + (hi4 << 3);
    rb[i] = (wn + i * 16 + lo16) * LDK + (hi4 << 3);
  }

  f32x4 acc[4][4];
  const f32x4 z4 = {0.f, 0.f, 0.f, 0.f};
#pragma unroll
  for (int i = 0; i < 4; ++i)
#pragma unroll
    for (int j = 0; j < 4; ++j) acc[i][j] = z4;

  float4 av[4], bv[4];
#pragma unroll
  for (int v = 0; v < 4; ++v) {           // prologue: tile k0=0
    av[v] = *(const float4*)(pa[v]);
    bv[v] = *(const float4*)(pb[v]);
  }

  for (int k0 = 0; k0 < K; k0 += 32) {
    __syncthreads();                      // previous compute done
    // split + LDS write (hi = truncated bf16; lo = bf16 of exact residual)
#pragma unroll
    for (int v = 0; v < 4; ++v) {
      float f[4] = {av[v].x, av[v].y, av[v].z, av[v].w};
      float g[4] = {bv[v].x, bv[v].y, bv[v].z, bv[v].w};
      unsigned int ha[4], hb[4], la[4], lb[4];
#pragma unroll
      for (int e = 0; e < 4; ++e) {
        unsigned int ua = __float_as_uint(f[e]) & 0xffff0000u;
        unsigned int ub = __float_as_uint(g[e]) & 0xffff0000u;
        ha[e] = ua; hb[e] = ub;
        la[e] = __float_as_uint(f[e] - __uint_as_float(ua));
        lb[e] = __float_as_uint(g[e] - __uint_as_float(ub));
      }
      uint2 hpa = {(ha[0] >> 16) | ha[1], (ha[2] >> 16) | ha[3]};
      uint2 lpa = {(la[0] >> 16) | (la[1] & 0xffff0000u),
                   (la[2] >> 16) | (la[3] & 0xffff0000u)};
      uint2 hpb = {(hb[0] >> 16) | hb[1], (hb[2] >> 16) | hb[3]};
      uint2 lpb = {(lb[0] >> 16) | (lb[1] & 0xffff0000u),
                   (lb[2] >> 16) | (lb[3] & 0xffff0000u)};
      *(uint2*)&Ah[wofs[v]] = hpa;
      *(uint2*)&Al[wofs[v]] = lpa;
      *(uint2*)&Bh[wofs[v]] = hpb;
      *(uint2*)&Bl[wofs[v]] = lpb;
    }
    __syncthreads();                      // LDS ready
    // issue next-tile global loads early (overlap with MFMA below)
    if (k0 + 32 < K) {
#pragma unroll
      for (int v = 0; v < 4; ++v) {
        av[v] = *(const float4*)(pa[v] + k0 + 32);
        bv[v] = *(const float4*)(pb[v] + k0 + 32);
      }
    }
    // fragments
    short8 fah[4], fal[4], fbh[4], fbl[4];
#pragma unroll
    for (int i = 0; i < 4; ++i) {
      fah[i] = *(const short8*)&Ah[ra[i]];
      fal[i] = *(const short8*)&Al[ra[i]];
      fbh[i] = *(const short8*)&Bh[rb[i]];
      fbl[i] = *(const short8*)&Bl[rb[i]];
    }
#pragma unroll
    for (int i = 0; i < 4; ++i)
#pragma unroll
      for (int j = 0; j < 4; ++j) {
        acc[i][j] = __builtin_amdgcn_mfma_f32_16x16x32_bf16(fah[i], fbh[j], acc[i][j], 0, 0, 0);
        acc[i][j] = __builtin_amdgcn_mfma_f32_16x16x32_bf16(fal[i], fbh[j], acc[i][j], 0, 0, 0);
        acc[i][j] = __builtin_amdgcn_mfma_f32_16x16x32_bf16(fah[i], fbl[j], acc[i][j], 0, 0, 0);
      }
  }

  // epilogue: D col = lane&15, row = (lane>>4)*4 + reg
#pragma unroll
  for (int i = 0; i < 4; ++i) {
    const int row = m0 + wm + i * 16 + (hi4 << 2);
#pragma unroll
    for (int j = 0; j < 4; ++j) {
      float* cp = C + (size_t)row * N + n0 + wn + j * 16 + lo16;
      cp[0]            = acc[i][j][0];
      cp[(size_t)N]    = acc[i][j][1];
      cp[(size_t)2*N]  = acc[i][j][2];
      cp[(size_t)3*N]  = acc[i][j][3];
    }
  }
}

// ---------------------------------------------------------------------------
// RoPE + assemble bf16 operands for MFMA attention:
//   qb [t][h][d]      bf16 (2048 x 2048)
//   kb [j][g][d]      bf16 (2080 x 512), j=0 sink (not roped), j>2048 zero pad
//   vtb[g*128+d][j]   bf16 (512 x 2080) -- V TRANSPOSED, zero pad
// ---------------------------------------------------------------------------
__global__ void rope_prep_bf16(const float* __restrict__ qkv,
                               const float* __restrict__ cosb,
                               const float* __restrict__ sinb,
                               const float* __restrict__ ksink,
                               const float* __restrict__ vsink,
                               unsigned short* __restrict__ qb,
                               unsigned short* __restrict__ kb,
                               unsigned short* __restrict__ vtb) {
  const int NQ = T_SEQ * 2048;            // 4,194,304
  const int NK = JP * 512;                // 1,064,960
  int idx = blockIdx.x * 256 + threadIdx.x;
  if (idx < NQ) {
    int t = idx >> 11, rem = idx & 2047;
    int h = rem >> 7, d = rem & 127;
    int g = h >> 2, qi = h & 3;
    const float* src = qkv + (size_t)t * 3072 + g * 768 + qi * 128;
    float val;
    if (d < 64) {
      val = src[d] * cosb[t * 64 + d] - src[d + 64] * sinb[t * 64 + d];
    } else {
      int dd = d - 64;
      val = src[dd] * sinb[t * 64 + dd] + src[d] * cosb[t * 64 + dd];
    }
    qb[idx] = f2bf(val);
  } else if (idx < NQ + NK) {
    int r = idx - NQ;
    int j = r >> 9, rem = r & 511;
    int g = rem >> 7, d = rem & 127;
    float val;
    if (j == 0) {
      val = ksink[(g << 7) + d];
    } else if (j <= T_SEQ) {
      int t = j - 1;
      const float* src = qkv + (size_t)t * 3072 + g * 768 + 512;
      if (d < 64) {
        val = src[d] * cosb[t * 64 + d] - src[d + 64] * sinb[t * 64 + d];
      } else {
        int dd = d - 64;
        val = src[dd] * sinb[t * 64 + dd] + src[d] * cosb[t * 64 + dd];
      }
    } else {
      val = 0.f;                          // zero pad: MFMA-safe
    }
    kb[r] = f2bf(val);
  } else {
    int r = idx - NQ - NK;
    int j = r >> 9, rem = r & 511;
    int g = rem >> 7, d = rem & 127;
    float val;
    if (j == 0)            val = vsink[(g << 7) + d];
    else if (j <= T_SEQ)   val = qkv[(size_t)(j - 1) * 3072 + g * 768 + 640 + d];
    else                   val = 0.f;
    vtb[(size_t)(g * 128 + d) * JP + j] = f2bf(val);
  }
}

// ---------------------------------------------------------------------------
// MFMA flash attention (bf16 in, f32 accum).  (unchanged this round)
// ---------------------------------------------------------------------------
__global__ __launch_bounds__(256) void attn_mfma_bf16(const unsigned short* __restrict__ qb,
                                                      const unsigned short* __restrict__ kb,
                                                      const unsigned short* __restrict__ vtb,
                                                      float* __restrict__ of) {
  const int bid  = blockIdx.x;
  const int tile = bid >> 2;
  const int g    = bid & 3;
  const int wv   = threadIdx.x >> 6;      // head within group
  const int h    = g * 4 + wv;
  const int lane = threadIdx.x & 63;
  const int lo   = lane & 15;
  const int hi   = lane >> 4;
  const int t0   = tile << 4;
  const int t    = t0 + lo;               // this lane's q row

  short8 qfrag[4];
  {
    const unsigned short* qp = qb + (size_t)t * 2048 + h * 128 + (hi << 3);
#pragma unroll
    for (int d0 = 0; d0 < 4; ++d0) qfrag[d0] = *(const short8*)(qp + d0 * 32);
  }

  f32x4 acc[8];
  const f32x4 z4 = {0.f, 0.f, 0.f, 0.f};
#pragma unroll
  for (int dt = 0; dt < 8; ++dt) acc[dt] = z4;

  float m = -1e4f, l = 0.f;

  int jlo = t0 - 1022; if (jlo < 0) jlo = 0;
  const int jb0  = jlo & ~31;
  const int jmax = t0 + 16;
  const int jrowA = ((lo >> 2) << 3) + (lo & 3);

  for (int jb = jb0; jb <= jmax; jb += 32) {
    const unsigned short* kbase = kb + (size_t)(jb + jrowA) * 512 + g * 128 + (hi << 3);
    f32x4 sa = z4, sb = z4;
#pragma unroll
    for (int d0 = 0; d0 < 4; ++d0) {
      short8 ka = *(const short8*)(kbase + d0 * 32);
      short8 kB = *(const short8*)(kbase + 4 * 512 + d0 * 32);
      sa = __builtin_amdgcn_mfma_f32_16x16x32_bf16(ka, qfrag[d0], sa, 0, 0, 0);
      sb = __builtin_amdgcn_mfma_f32_16x16x32_bf16(kB, qfrag[d0], sb, 0, 0, 0);
    }

    float z[8];
    const int jbase = jb + (hi << 3);
    const bool interior = (jb >= t0 - 1007) && (jb <= t0 - 30);
    if (interior) {
#pragma unroll
      for (int r = 0; r < 4; ++r) { z[r] = sa[r] * SL_F; z[r + 4] = sb[r] * SL_F; }
    } else {
#pragma unroll
      for (int r = 0; r < 8; ++r) {
        float sv = (r < 4) ? sa[r] : sb[r - 4];
        int j = jbase + r;
        bool valid = (j <= t + 1) && (j >= t - 1022);
        z[r] = valid ? sv * SL_F : -1e30f;
      }
    }

    float cm = z[0];
#pragma unroll
    for (int r = 1; r < 8; ++r) cm = fmaxf(cm, z[r]);
    cm = fmaxf(cm, __shfl_xor(cm, 16, 64));
    cm = fmaxf(cm, __shfl_xor(cm, 32, 64));
    float mn = fmaxf(m, cm);
    float a = exp2f(m - mn);
    float p[8], ls = 0.f;
#pragma unroll
    for (int r = 0; r < 8; ++r) { p[r] = exp2f(z[r] - mn); ls += p[r]; }
    ls += __shfl_xor(ls, 16, 64);
    ls += __shfl_xor(ls, 32, 64);
    l = l * a + ls;
    m = mn;
#pragma unroll
    for (int dt = 0; dt < 8; ++dt) acc[dt] *= a;

    short8 pfrag;
#pragma unroll
    for (int e = 0; e < 8; ++e) pfrag[e] = (short)f2bf(p[e]);

    const unsigned short* vbase = vtb + (size_t)(g * 128 + lo) * JP + jb + (hi << 3);
#pragma unroll
    for (int dt = 0; dt < 8; ++dt) {
      short8 vf = *(const short8*)(vbase + (size_t)dt * 16 * JP);
      acc[dt] = __builtin_amdgcn_mfma_f32_16x16x32_bf16(vf, pfrag, acc[dt], 0, 0, 0);
    }
  }

  const float inv = 1.f / l;
  float* op = of + (size_t)t * 2048 + h * 128 + (hi << 2);
#pragma unroll
  for (int dt = 0; dt < 8; ++dt) {
    f32x4 o4 = acc[dt] * inv;
    *(f32x4*)(op + dt * 16) = o4;
  }
}

extern "C" void kernel_launch(void* const* d_in, const int* in_sizes, int n_in,
                              void* d_out, int out_size, void* d_ws, size_t ws_size,
                              hipStream_t stream) {
  const float* x     = (const float*)d_in[0];   // (2048, 2048) f32
  const float* cosb  = (const float*)d_in[1];   // (2048, 64)   f32
  const float* sinb  = (const float*)d_in[2];   // (2048, 64)   f32
  const float* Wa    = (const float*)d_in[3];   // (3072, 2048) f32
  const float* Wp    = (const float*)d_in[4];   // (2048, 2048) f32
  const float* ksink = (const float*)d_in[5];   // (512,)       f32
  const float* vsink = (const float*)d_in[6];   // (512,)       f32
  float* y = (float*)d_out;                     // (2048, 2048) f32

  char* ws = (char*)d_ws;
  float*          qkv = (float*)ws;                         // 25,165,824 B
  unsigned short* qb  = (unsigned short*)(ws + 25165824);   //  8,388,608 B
  unsigned short* kbb = (unsigned short*)(ws + 33554432);   //  2,129,920 B
  unsigned short* vtb = (unsigned short*)(ws + 35684352);   //  2,129,920 B
  float*          of  = (float*)(ws + 37814272);            // 16,777,216 B -> 54,591,488 total

  // 1. qkv = x @ W_attn^T  (split-f32 MFMA)
  gemm_bt_split<<<dim3(24, 16), 256, 0, stream>>>(x, Wa, qkv, 2048, 3072, 2048);
  // 2. RoPE + bf16 operand assembly (q, k, V^T; zero-padded to JP)
  rope_prep_bf16<<<24704, 256, 0, stream>>>(qkv, cosb, sinb, ksink, vsink, qb, kbb, vtb);
  // 3. MFMA flash attention
  attn_mfma_bf16<<<512, 256, 0, stream>>>(qb, kbb, vtb, of);
  // 4. y = o @ W_proj^T  (split-f32 MFMA)
  gemm_bt_split<<<dim3(16, 16), 256, 0, stream>>>(of, Wp, y, 2048, 2048, 2048);
}

// Round 3
// 389.560 us; speedup vs baseline: 4.5494x; 1.0309x over previous
//
#include <hip/hip_runtime.h>

#define T_SEQ  2048
#define TK_SEQ 2049
#define JP     2080                       // padded key length (zeroed pads)
#define SCALE_F 0.08838834764831845f
#define SL_F    0.12751744f               // SCALE * log2(e)
#define THR_L2  11.0f                     // defer-max threshold (log2 domain)

typedef __attribute__((ext_vector_type(8))) short short8;
typedef __attribute__((ext_vector_type(4))) float f32x4;

__device__ __forceinline__ unsigned short f2bf(float f) {
  unsigned int u = __float_as_uint(f);
  u += 0x7fff + ((u >> 16) & 1);          // round-to-nearest-even
  return (unsigned short)(u >> 16);
}

// ---------------------------------------------------------------------------
// split_pack: f32 -> interleaved split groups of 4: {4x bf16 hi (trunc),
// 4x bf16 lo (RNE of residual)} = 16 B per 4 floats.  Two ranges per launch.
// ---------------------------------------------------------------------------
__global__ __launch_bounds__(256) void split_pack(const float4* __restrict__ s0,
                                                  uint4* __restrict__ d0, int n0,
                                                  const float4* __restrict__ s1,
                                                  uint4* __restrict__ d1, int n1) {
  int i = blockIdx.x * 256 + threadIdx.x;
  const float4* s; uint4* d; int k;
  if (i < n0) { s = s0; d = d0; k = i; }
  else { k = i - n0; if (k >= n1) return; s = s1; d = d1; }
  float4 f = s[k];
  unsigned int h0 = __float_as_uint(f.x) & 0xffff0000u;
  unsigned int h1 = __float_as_uint(f.y) & 0xffff0000u;
  unsigned int h2 = __float_as_uint(f.z) & 0xffff0000u;
  unsigned int h3 = __float_as_uint(f.w) & 0xffff0000u;
  unsigned int l0 = f2bf(f.x - __uint_as_float(h0));
  unsigned int l1 = f2bf(f.y - __uint_as_float(h1));
  unsigned int l2 = f2bf(f.z - __uint_as_float(h2));
  unsigned int l3 = f2bf(f.w - __uint_as_float(h3));
  uint4 o;
  o.x = (h0 >> 16) | (h1 & 0xffff0000u);
  o.y = (h2 >> 16) | (h3 & 0xffff0000u);
  o.z = l0 | (l1 << 16);
  o.w = l2 | (l3 << 16);
  d[k] = o;
}

// ---------------------------------------------------------------------------
// Split-f32 MFMA GEMM, pre-split operands: C[M,N] = A[M,K] * B[N,K]^T.
// As/Bs are interleaved split arrays (16 B per 4 elems).  C ~= AhBh+AlBh+AhBl.
// 128x128 tile, 4 waves (2x2), 4x4 frags mfma_f32_16x16x32_bf16, BK=32.
// Staging: one dwordx4 load + 2x ds_write_b64 per matrix per v -- no VALU.
// ---------------------------------------------------------------------------
#define LDK 56

__global__ __launch_bounds__(256, 2) void gemm_sp(const uint4* __restrict__ As,
                                                  const uint4* __restrict__ Bs,
                                                  float* __restrict__ C,
                                                  int M, int N, int K) {
  __shared__ unsigned short Ah[128 * LDK], Al[128 * LDK];
  __shared__ unsigned short Bh[128 * LDK], Bl[128 * LDK];

  const int tid  = threadIdx.x;
  const int lane = tid & 63;
  const int wid  = tid >> 6;
  const int wm   = (wid >> 1) << 6;
  const int wn   = (wid & 1) << 6;
  const int lo16 = lane & 15;
  const int hi4  = lane >> 4;
  const int m0   = blockIdx.y << 7;
  const int n0   = blockIdx.x << 7;
  const int Kg   = K >> 2;                // groups of 4 per row

  const uint4* pa[4];
  const uint4* pb[4];
  int wofs[4];
#pragma unroll
  for (int v = 0; v < 4; ++v) {
    int id = (v << 8) + tid;
    int r  = id >> 3;
    int kc = (id & 7) << 2;
    pa[v]   = As + (size_t)(m0 + r) * Kg + (kc >> 2);
    pb[v]   = Bs + (size_t)(n0 + r) * Kg + (kc >> 2);
    wofs[v] = r * LDK + kc;
  }

  int ra[4], rb[4];
#pragma unroll
  for (int i = 0; i < 4; ++i) {
    ra[i] = (wm + i * 16 + lo16) * LDK + (hi4 << 3);
    rb[i] = (wn + i * 16 + lo16) * LDK + (hi4 << 3);
  }

  f32x4 acc[4][4];
  const f32x4 z4 = {0.f, 0.f, 0.f, 0.f};
#pragma unroll
  for (int i = 0; i < 4; ++i)
#pragma unroll
    for (int j = 0; j < 4; ++j) acc[i][j] = z4;

  uint4 av[4], bv[4];
#pragma unroll
  for (int v = 0; v < 4; ++v) { av[v] = pa[v][0]; bv[v] = pb[v][0]; }

  for (int k0 = 0; k0 < K; k0 += 32) {
    __syncthreads();
#pragma unroll
    for (int v = 0; v < 4; ++v) {
      uint2 ah = {av[v].x, av[v].y}, al = {av[v].z, av[v].w};
      uint2 bh = {bv[v].x, bv[v].y}, bl = {bv[v].z, bv[v].w};
      *(uint2*)&Ah[wofs[v]] = ah;
      *(uint2*)&Al[wofs[v]] = al;
      *(uint2*)&Bh[wofs[v]] = bh;
      *(uint2*)&Bl[wofs[v]] = bl;
    }
    __syncthreads();
    if (k0 + 32 < K) {
      int kg = (k0 + 32) >> 2;
#pragma unroll
      for (int v = 0; v < 4; ++v) { av[v] = pa[v][kg]; bv[v] = pb[v][kg]; }
    }
    short8 fah[4], fal[4], fbh[4], fbl[4];
#pragma unroll
    for (int i = 0; i < 4; ++i) {
      fah[i] = *(const short8*)&Ah[ra[i]];
      fal[i] = *(const short8*)&Al[ra[i]];
      fbh[i] = *(const short8*)&Bh[rb[i]];
      fbl[i] = *(const short8*)&Bl[rb[i]];
    }
#pragma unroll
    for (int i = 0; i < 4; ++i)
#pragma unroll
      for (int j = 0; j < 4; ++j) {
        acc[i][j] = __builtin_amdgcn_mfma_f32_16x16x32_bf16(fah[i], fbh[j], acc[i][j], 0, 0, 0);
        acc[i][j] = __builtin_amdgcn_mfma_f32_16x16x32_bf16(fal[i], fbh[j], acc[i][j], 0, 0, 0);
        acc[i][j] = __builtin_amdgcn_mfma_f32_16x16x32_bf16(fah[i], fbl[j], acc[i][j], 0, 0, 0);
      }
  }

#pragma unroll
  for (int i = 0; i < 4; ++i) {
    const int row = m0 + wm + i * 16 + (hi4 << 2);
#pragma unroll
    for (int j = 0; j < 4; ++j) {
      float* cp = C + (size_t)row * N + n0 + wn + j * 16 + lo16;
      cp[0]            = acc[i][j][0];
      cp[(size_t)N]    = acc[i][j][1];
      cp[(size_t)2*N]  = acc[i][j][2];
      cp[(size_t)3*N]  = acc[i][j][3];
    }
  }
}

// ---------------------------------------------------------------------------
// rope2: RoPE + bf16 operand assembly, all sections coalesced.
//   Sect Q  (blocks [0,4096)):        qb[t][h][d], pair-vectorized
//   Sect K  (blocks [4096,5120)):     kb[j][g][d], j=t+1
//   Sect KE (blocks [5120,5184)):     kb sink row j=0 + zero pads j>2048
//   Sect V  (blocks [5184,5249)):     vtb[g*128+d][j] via LDS transpose tile
// ---------------------------------------------------------------------------
#define RB_Q  4096
#define RB_K  1024
#define RB_KE 64
#define RB_V  65

__global__ __launch_bounds__(256) void rope2(const float* __restrict__ qkv,
                                             const float* __restrict__ cosb,
                                             const float* __restrict__ sinb,
                                             const float* __restrict__ ksink,
                                             const float* __restrict__ vsink,
                                             unsigned short* __restrict__ qb,
                                             unsigned short* __restrict__ kb,
                                             unsigned short* __restrict__ vtb) {
  __shared__ unsigned short tl[512 * 33];
  const int bid = blockIdx.x, tid = threadIdx.x;
  if (bid < RB_Q) {
    int idx = bid * 256 + tid;            // 1,048,576: (t, h, dp/2)
    int t = idx >> 9, rem = idx & 511;
    int h = rem >> 5, dp = (rem & 31) << 1;
    int g = h >> 2, qi = h & 3;
    const float* src = qkv + (size_t)t * 3072 + g * 768 + qi * 128;
    float2 x1 = *(const float2*)(src + dp);
    float2 x2 = *(const float2*)(src + 64 + dp);
    float2 c  = *(const float2*)(cosb + t * 64 + dp);
    float2 s  = *(const float2*)(sinb + t * 64 + dp);
    ushort2 o1 = { f2bf(x1.x * c.x - x2.x * s.x), f2bf(x1.y * c.y - x2.y * s.y) };
    ushort2 o2 = { f2bf(x1.x * s.x + x2.x * c.x), f2bf(x1.y * s.y + x2.y * c.y) };
    *(ushort2*)(qb + (size_t)t * 2048 + h * 128 + dp)      = o1;
    *(ushort2*)(qb + (size_t)t * 2048 + h * 128 + 64 + dp) = o2;
  } else if (bid < RB_Q + RB_K) {
    int idx = (bid - RB_Q) * 256 + tid;   // 262,144: (t, g, dp/2)
    int t = idx >> 7, rem = idx & 127;
    int g = rem >> 5, dp = (rem & 31) << 1;
    const float* src = qkv + (size_t)t * 3072 + g * 768 + 512;
    float2 x1 = *(const float2*)(src + dp);
    float2 x2 = *(const float2*)(src + 64 + dp);
    float2 c  = *(const float2*)(cosb + t * 64 + dp);
    float2 s  = *(const float2*)(sinb + t * 64 + dp);
    ushort2 o1 = { f2bf(x1.x * c.x - x2.x * s.x), f2bf(x1.y * c.y - x2.y * s.y) };
    ushort2 o2 = { f2bf(x1.x * s.x + x2.x * c.x), f2bf(x1.y * s.y + x2.y * c.y) };
    size_t base = (size_t)(t + 1) * 512 + g * 128 + dp;
    *(ushort2*)(kb + base)      = o1;
    *(ushort2*)(kb + base + 64) = o2;
  } else if (bid < RB_Q + RB_K + RB_KE) {
    int idx = (bid - RB_Q - RB_K) * 256 + tid;   // 16,384: sink + pads
    int jj = idx >> 9, c = idx & 511;
    if (jj == 0) kb[c] = f2bf(ksink[c]);
    else         kb[(size_t)(2048 + jj) * 512 + c] = 0;
  } else {
    int b  = bid - RB_Q - RB_K - RB_KE;   // 0..64, j-tile of 32
    int j0 = b << 5;
#pragma unroll 4
    for (int st = 0; st < 64; ++st) {
      int id = st * 256 + tid;            // 16,384 = 32 j x 512 gd
      int jj = id >> 9, c = id & 511;
      int j = j0 + jj;
      float val;
      if (j == 0)          val = vsink[c];
      else if (j <= T_SEQ) val = qkv[(size_t)(j - 1) * 3072 + (c >> 7) * 768 + 640 + (c & 127)];
      else                 val = 0.f;
      tl[c * 33 + jj] = f2bf(val);
    }
    __syncthreads();
#pragma unroll 4
    for (int st = 0; st < 32; ++st) {
      int id = st * 256 + tid;            // 8,192 = 512 rows x 16 jp-pairs
      int row = id >> 4, jp = (id & 15) << 1;
      ushort2 w = { tl[row * 33 + jp], tl[row * 33 + jp + 1] };
      *(ushort2*)(vtb + (size_t)row * JP + j0 + jp) = w;
    }
  }
}

// ---------------------------------------------------------------------------
// MFMA flash attention (bf16 in, f32 accum) with defer-max + per-lane l.
// Output written PRE-SPLIT (interleaved hi/lo groups) for gemm_sp.
// ---------------------------------------------------------------------------
__global__ __launch_bounds__(256) void attn_mfma_bf16(const unsigned short* __restrict__ qb,
                                                      const unsigned short* __restrict__ kb,
                                                      const unsigned short* __restrict__ vtb,
                                                      uint4* __restrict__ ofs) {
  const int bid  = blockIdx.x;
  const int tile = bid >> 2;
  const int g    = bid & 3;
  const int wv   = threadIdx.x >> 6;
  const int h    = g * 4 + wv;
  const int lane = threadIdx.x & 63;
  const int lo   = lane & 15;
  const int hi   = lane >> 4;
  const int t0   = tile << 4;
  const int t    = t0 + lo;

  short8 qfrag[4];
  {
    const unsigned short* qp = qb + (size_t)t * 2048 + h * 128 + (hi << 3);
#pragma unroll
    for (int d0 = 0; d0 < 4; ++d0) qfrag[d0] = *(const short8*)(qp + d0 * 32);
  }

  f32x4 acc[8];
  const f32x4 z4 = {0.f, 0.f, 0.f, 0.f};
#pragma unroll
  for (int dt = 0; dt < 8; ++dt) acc[dt] = z4;

  float m = -1e4f, l = 0.f;               // l is PER-LANE partial (own 8 js)

  int jlo = t0 - 1022; if (jlo < 0) jlo = 0;
  const int jb0  = jlo & ~31;
  const int jmax = t0 + 16;
  const int jrowA = ((lo >> 2) << 3) + (lo & 3);

  for (int jb = jb0; jb <= jmax; jb += 32) {
    const unsigned short* kbase = kb + (size_t)(jb + jrowA) * 512 + g * 128 + (hi << 3);
    f32x4 sa = z4, sb = z4;
#pragma unroll
    for (int d0 = 0; d0 < 4; ++d0) {
      short8 ka = *(const short8*)(kbase + d0 * 32);
      short8 kB = *(const short8*)(kbase + 4 * 512 + d0 * 32);
      sa = __builtin_amdgcn_mfma_f32_16x16x32_bf16(ka, qfrag[d0], sa, 0, 0, 0);
      sb = __builtin_amdgcn_mfma_f32_16x16x32_bf16(kB, qfrag[d0], sb, 0, 0, 0);
    }

    float z[8];
    const int jbase = jb + (hi << 3);
    const bool interior = (jb >= t0 - 1007) && (jb <= t0 - 30);
    if (interior) {
#pragma unroll
      for (int r = 0; r < 4; ++r) { z[r] = sa[r] * SL_F; z[r + 4] = sb[r] * SL_F; }
    } else {
#pragma unroll
      for (int r = 0; r < 8; ++r) {
        float sv = (r < 4) ? sa[r] : sb[r - 4];
        int j = jbase + r;
        bool valid = (j <= t + 1) && (j >= t - 1022);
        z[r] = valid ? sv * SL_F : -1e30f;
      }
    }

    // chunk-local max over own 8 (compiler fuses to v_max3 tree)
    float lmax = fmaxf(fmaxf(fmaxf(z[0], z[1]), fmaxf(z[2], z[3])),
                       fmaxf(fmaxf(z[4], z[5]), fmaxf(z[6], z[7])));
    // defer-max: skip cross-lane max + rescale when bounded
    if (!__all(lmax <= m + THR_L2)) {
      float cm = lmax;
      cm = fmaxf(cm, __shfl_xor(cm, 16, 64));
      cm = fmaxf(cm, __shfl_xor(cm, 32, 64));
      float mn = fmaxf(m, cm);
      float a  = exp2f(m - mn);
      l *= a;
#pragma unroll
      for (int dt = 0; dt < 8; ++dt) acc[dt] *= a;
      m = mn;
    }

    float p[8];
#pragma unroll
    for (int r = 0; r < 8; ++r) { p[r] = exp2f(z[r] - m); l += p[r]; }

    short8 pfrag;
#pragma unroll
    for (int e = 0; e < 8; ++e) pfrag[e] = (short)f2bf(p[e]);

    const unsigned short* vbase = vtb + (size_t)(g * 128 + lo) * JP + jb + (hi << 3);
#pragma unroll
    for (int dt = 0; dt < 8; ++dt) {
      short8 vf = *(const short8*)(vbase + (size_t)dt * 16 * JP);
      acc[dt] = __builtin_amdgcn_mfma_f32_16x16x32_bf16(vf, pfrag, acc[dt], 0, 0, 0);
    }
  }

  float lt = l;
  lt += __shfl_xor(lt, 16, 64);
  lt += __shfl_xor(lt, 32, 64);
  const float inv = 1.f / lt;

  // epilogue: write pre-split interleaved groups (hi trunc / lo RNE)
  const size_t elem = (size_t)t * 2048 + h * 128 + (hi << 2);
#pragma unroll
  for (int dt = 0; dt < 8; ++dt) {
    f32x4 o4 = acc[dt] * inv;
    unsigned int h0 = __float_as_uint(o4[0]) & 0xffff0000u;
    unsigned int h1 = __float_as_uint(o4[1]) & 0xffff0000u;
    unsigned int h2 = __float_as_uint(o4[2]) & 0xffff0000u;
    unsigned int h3 = __float_as_uint(o4[3]) & 0xffff0000u;
    unsigned int l0 = f2bf(o4[0] - __uint_as_float(h0));
    unsigned int l1 = f2bf(o4[1] - __uint_as_float(h1));
    unsigned int l2 = f2bf(o4[2] - __uint_as_float(h2));
    unsigned int l3 = f2bf(o4[3] - __uint_as_float(h3));
    uint4 pk;
    pk.x = (h0 >> 16) | (h1 & 0xffff0000u);
    pk.y = (h2 >> 16) | (h3 & 0xffff0000u);
    pk.z = l0 | (l1 << 16);
    pk.w = l2 | (l3 << 16);
    ofs[(elem >> 2) + dt * 4] = pk;
  }
}

extern "C" void kernel_launch(void* const* d_in, const int* in_sizes, int n_in,
                              void* d_out, int out_size, void* d_ws, size_t ws_size,
                              hipStream_t stream) {
  const float* x     = (const float*)d_in[0];   // (2048, 2048) f32
  const float* cosb  = (const float*)d_in[1];   // (2048, 64)   f32
  const float* sinb  = (const float*)d_in[2];   // (2048, 64)   f32
  const float* Wa    = (const float*)d_in[3];   // (3072, 2048) f32
  const float* Wp    = (const float*)d_in[4];   // (2048, 2048) f32
  const float* ksink = (const float*)d_in[5];   // (512,)       f32
  const float* vsink = (const float*)d_in[6];   // (512,)       f32
  float* y = (float*)d_out;                     // (2048, 2048) f32

  // Workspace aliasing plan (peak 67,108,864 B; stream-serial stages):
  //  [0,        25165824): qkv f32            (stages 2-3)
  //  [0,        16777216): wps (Wp split)     (stage 4+; qkv dead after rope)
  //  [25165824, 50331648): was (Wa split)     (stages 1-2)
  //  [25165824, 41943040): ofs (attn out)     (stage 5+; was dead after GEMM1)
  //  [50331648, 67108864): xs  (x split)      (stages 1-2)
  //  [50331648, 62980096): qb/kb/vtb          (stage 3+; xs dead after GEMM1)
  char* ws = (char*)d_ws;
  float*          qkv = (float*)ws;
  uint4*          wps = (uint4*)ws;
  uint4*          was = (uint4*)(ws + 25165824);
  uint4*          ofs = (uint4*)(ws + 25165824);
  uint4*          xs  = (uint4*)(ws + 50331648);
  unsigned short* qb  = (unsigned short*)(ws + 50331648);
  unsigned short* kbb = (unsigned short*)(ws + 58720256);
  unsigned short* vtb = (unsigned short*)(ws + 60850176);

  // 1. pre-split x and Wa (interleaved hi/lo)
  split_pack<<<10240, 256, 0, stream>>>((const float4*)x, xs, 1048576,
                                        (const float4*)Wa, was, 1572864);
  // 2. qkv = x @ Wa^T  (split MFMA, pre-split operands)
  gemm_sp<<<dim3(24, 16), 256, 0, stream>>>(xs, was, qkv, 2048, 3072, 2048);
  // 3. RoPE + operand assembly (coalesced; LDS-transposed V)
  rope2<<<RB_Q + RB_K + RB_KE + RB_V, 256, 0, stream>>>(qkv, cosb, sinb, ksink, vsink,
                                                        qb, kbb, vtb);
  // 4. pre-split Wp (into dead qkv region)
  split_pack<<<4096, 256, 0, stream>>>((const float4*)Wp, wps, 1048576,
                                       (const float4*)Wp, wps, 0);
  // 5. MFMA flash attention (writes pre-split output)
  attn_mfma_bf16<<<512, 256, 0, stream>>>(qb, kbb, vtb, ofs);
  // 6. y = o @ Wp^T
  gemm_sp<<<dim3(16, 16), 256, 0, stream>>>(ofs, wps, y, 2048, 2048, 2048);
}

// Round 4
// 381.140 us; speedup vs baseline: 4.6499x; 1.0221x over previous
//
#include <hip/hip_runtime.h>

#define T_SEQ  2048
#define TK_SEQ 2049
#define JP     2080                       // padded key length (zeroed pads)
#define SCALE_F 0.08838834764831845f
#define SL_F    0.12751744f               // SCALE * log2(e)
#define THR_L2  11.0f                     // defer-max threshold (log2 domain)

typedef __attribute__((ext_vector_type(8))) short short8;
typedef __attribute__((ext_vector_type(4))) float f32x4;

__device__ __forceinline__ unsigned short f2bf(float f) {
  unsigned int u = __float_as_uint(f);
  u += 0x7fff + ((u >> 16) & 1);          // round-to-nearest-even
  return (unsigned short)(u >> 16);
}

// ---------------------------------------------------------------------------
// split_pack: f32 -> interleaved split groups of 4: {4x bf16 hi (trunc),
// 4x bf16 lo (RNE of residual)} = 16 B per 4 floats.  Two ranges per launch.
// ---------------------------------------------------------------------------
__global__ __launch_bounds__(256) void split_pack(const float4* __restrict__ s0,
                                                  uint4* __restrict__ d0, int n0,
                                                  const float4* __restrict__ s1,
                                                  uint4* __restrict__ d1, int n1) {
  int i = blockIdx.x * 256 + threadIdx.x;
  const float4* s; uint4* d; int k;
  if (i < n0) { s = s0; d = d0; k = i; }
  else { k = i - n0; if (k >= n1) return; s = s1; d = d1; }
  float4 f = s[k];
  unsigned int h0 = __float_as_uint(f.x) & 0xffff0000u;
  unsigned int h1 = __float_as_uint(f.y) & 0xffff0000u;
  unsigned int h2 = __float_as_uint(f.z) & 0xffff0000u;
  unsigned int h3 = __float_as_uint(f.w) & 0xffff0000u;
  unsigned int l0 = f2bf(f.x - __uint_as_float(h0));
  unsigned int l1 = f2bf(f.y - __uint_as_float(h1));
  unsigned int l2 = f2bf(f.z - __uint_as_float(h2));
  unsigned int l3 = f2bf(f.w - __uint_as_float(h3));
  uint4 o;
  o.x = (h0 >> 16) | (h1 & 0xffff0000u);
  o.y = (h2 >> 16) | (h3 & 0xffff0000u);
  o.z = l0 | (l1 << 16);
  o.w = l2 | (l3 << 16);
  d[k] = o;
}

// ---------------------------------------------------------------------------
// Split-f32 MFMA GEMM, pre-split operands: C[M,N] = A[M,K] * B[N,K]^T.
// 128x64 tile (was 128x128): GEMM1 768 blocks / GEMM2 512 blocks -> 3 / 2
// blocks per CU (12 / 8 waves per CU) for latency hiding.  4 waves (2Mx2N),
// per-wave 64x32 output = 4x2 frags x 3 MFMA passes, BK=32.
// ---------------------------------------------------------------------------
#define LDK 56

__global__ __launch_bounds__(256, 3) void gemm_sp(const uint4* __restrict__ As,
                                                  const uint4* __restrict__ Bs,
                                                  float* __restrict__ C,
                                                  int M, int N, int K) {
  __shared__ unsigned short Ah[128 * LDK], Al[128 * LDK];
  __shared__ unsigned short Bh[64 * LDK],  Bl[64 * LDK];

  const int tid  = threadIdx.x;
  const int lane = tid & 63;
  const int wid  = tid >> 6;
  const int wm   = (wid >> 1) << 6;       // 0 / 64
  const int wn   = (wid & 1) << 5;        // 0 / 32
  const int lo16 = lane & 15;
  const int hi4  = lane >> 4;
  const int m0   = blockIdx.y << 7;
  const int n0   = blockIdx.x << 6;
  const int Kg   = K >> 2;                // groups of 4 per row

  const uint4* pa[4];
  const uint4* pb[2];
  int waofs[4], wbofs[2];
#pragma unroll
  for (int v = 0; v < 4; ++v) {
    int id = (v << 8) + tid;
    int r  = id >> 3;
    int kc = (id & 7) << 2;
    pa[v]    = As + (size_t)(m0 + r) * Kg + (kc >> 2);
    waofs[v] = r * LDK + kc;
  }
#pragma unroll
  for (int v = 0; v < 2; ++v) {
    int id = (v << 8) + tid;
    int r  = id >> 3;
    int kc = (id & 7) << 2;
    pb[v]    = Bs + (size_t)(n0 + r) * Kg + (kc >> 2);
    wbofs[v] = r * LDK + kc;
  }

  int ra[4], rb[2];
#pragma unroll
  for (int i = 0; i < 4; ++i) ra[i] = (wm + i * 16 + lo16) * LDK + (hi4 << 3);
#pragma unroll
  for (int j = 0; j < 2; ++j) rb[j] = (wn + j * 16 + lo16) * LDK + (hi4 << 3);

  f32x4 acc[4][2];
  const f32x4 z4 = {0.f, 0.f, 0.f, 0.f};
#pragma unroll
  for (int i = 0; i < 4; ++i)
#pragma unroll
    for (int j = 0; j < 2; ++j) acc[i][j] = z4;

  uint4 av[4], bv[2];
#pragma unroll
  for (int v = 0; v < 4; ++v) av[v] = pa[v][0];
#pragma unroll
  for (int v = 0; v < 2; ++v) bv[v] = pb[v][0];

  for (int k0 = 0; k0 < K; k0 += 32) {
    __syncthreads();
#pragma unroll
    for (int v = 0; v < 4; ++v) {
      uint2 ah = {av[v].x, av[v].y}, al = {av[v].z, av[v].w};
      *(uint2*)&Ah[waofs[v]] = ah;
      *(uint2*)&Al[waofs[v]] = al;
    }
#pragma unroll
    for (int v = 0; v < 2; ++v) {
      uint2 bh = {bv[v].x, bv[v].y}, bl = {bv[v].z, bv[v].w};
      *(uint2*)&Bh[wbofs[v]] = bh;
      *(uint2*)&Bl[wbofs[v]] = bl;
    }
    __syncthreads();
    if (k0 + 32 < K) {
      int kg = (k0 + 32) >> 2;
#pragma unroll
      for (int v = 0; v < 4; ++v) av[v] = pa[v][kg];
#pragma unroll
      for (int v = 0; v < 2; ++v) bv[v] = pb[v][kg];
    }
    short8 fah[4], fal[4], fbh[2], fbl[2];
#pragma unroll
    for (int i = 0; i < 4; ++i) {
      fah[i] = *(const short8*)&Ah[ra[i]];
      fal[i] = *(const short8*)&Al[ra[i]];
    }
#pragma unroll
    for (int j = 0; j < 2; ++j) {
      fbh[j] = *(const short8*)&Bh[rb[j]];
      fbl[j] = *(const short8*)&Bl[rb[j]];
    }
#pragma unroll
    for (int i = 0; i < 4; ++i)
#pragma unroll
      for (int j = 0; j < 2; ++j) {
        acc[i][j] = __builtin_amdgcn_mfma_f32_16x16x32_bf16(fah[i], fbh[j], acc[i][j], 0, 0, 0);
        acc[i][j] = __builtin_amdgcn_mfma_f32_16x16x32_bf16(fal[i], fbh[j], acc[i][j], 0, 0, 0);
        acc[i][j] = __builtin_amdgcn_mfma_f32_16x16x32_bf16(fah[i], fbl[j], acc[i][j], 0, 0, 0);
      }
  }

#pragma unroll
  for (int i = 0; i < 4; ++i) {
    const int row = m0 + wm + i * 16 + (hi4 << 2);
#pragma unroll
    for (int j = 0; j < 2; ++j) {
      float* cp = C + (size_t)row * N + n0 + wn + j * 16 + lo16;
      cp[0]            = acc[i][j][0];
      cp[(size_t)N]    = acc[i][j][1];
      cp[(size_t)2*N]  = acc[i][j][2];
      cp[(size_t)3*N]  = acc[i][j][3];
    }
  }
}

// ---------------------------------------------------------------------------
// rope2: RoPE + bf16 operand assembly, all sections coalesced.  (unchanged)
// ---------------------------------------------------------------------------
#define RB_Q  4096
#define RB_K  1024
#define RB_KE 64
#define RB_V  65

__global__ __launch_bounds__(256) void rope2(const float* __restrict__ qkv,
                                             const float* __restrict__ cosb,
                                             const float* __restrict__ sinb,
                                             const float* __restrict__ ksink,
                                             const float* __restrict__ vsink,
                                             unsigned short* __restrict__ qb,
                                             unsigned short* __restrict__ kb,
                                             unsigned short* __restrict__ vtb) {
  __shared__ unsigned short tl[512 * 33];
  const int bid = blockIdx.x, tid = threadIdx.x;
  if (bid < RB_Q) {
    int idx = bid * 256 + tid;            // 1,048,576: (t, h, dp/2)
    int t = idx >> 9, rem = idx & 511;
    int h = rem >> 5, dp = (rem & 31) << 1;
    int g = h >> 2, qi = h & 3;
    const float* src = qkv + (size_t)t * 3072 + g * 768 + qi * 128;
    float2 x1 = *(const float2*)(src + dp);
    float2 x2 = *(const float2*)(src + 64 + dp);
    float2 c  = *(const float2*)(cosb + t * 64 + dp);
    float2 s  = *(const float2*)(sinb + t * 64 + dp);
    ushort2 o1 = { f2bf(x1.x * c.x - x2.x * s.x), f2bf(x1.y * c.y - x2.y * s.y) };
    ushort2 o2 = { f2bf(x1.x * s.x + x2.x * c.x), f2bf(x1.y * s.y + x2.y * c.y) };
    *(ushort2*)(qb + (size_t)t * 2048 + h * 128 + dp)      = o1;
    *(ushort2*)(qb + (size_t)t * 2048 + h * 128 + 64 + dp) = o2;
  } else if (bid < RB_Q + RB_K) {
    int idx = (bid - RB_Q) * 256 + tid;   // 262,144: (t, g, dp/2)
    int t = idx >> 7, rem = idx & 127;
    int g = rem >> 5, dp = (rem & 31) << 1;
    const float* src = qkv + (size_t)t * 3072 + g * 768 + 512;
    float2 x1 = *(const float2*)(src + dp);
    float2 x2 = *(const float2*)(src + 64 + dp);
    float2 c  = *(const float2*)(cosb + t * 64 + dp);
    float2 s  = *(const float2*)(sinb + t * 64 + dp);
    ushort2 o1 = { f2bf(x1.x * c.x - x2.x * s.x), f2bf(x1.y * c.y - x2.y * s.y) };
    ushort2 o2 = { f2bf(x1.x * s.x + x2.x * c.x), f2bf(x1.y * s.y + x2.y * c.y) };
    size_t base = (size_t)(t + 1) * 512 + g * 128 + dp;
    *(ushort2*)(kb + base)      = o1;
    *(ushort2*)(kb + base + 64) = o2;
  } else if (bid < RB_Q + RB_K + RB_KE) {
    int idx = (bid - RB_Q - RB_K) * 256 + tid;   // 16,384: sink + pads
    int jj = idx >> 9, c = idx & 511;
    if (jj == 0) kb[c] = f2bf(ksink[c]);
    else         kb[(size_t)(2048 + jj) * 512 + c] = 0;
  } else {
    int b  = bid - RB_Q - RB_K - RB_KE;   // 0..64, j-tile of 32
    int j0 = b << 5;
#pragma unroll 4
    for (int st = 0; st < 64; ++st) {
      int id = st * 256 + tid;            // 16,384 = 32 j x 512 gd
      int jj = id >> 9, c = id & 511;
      int j = j0 + jj;
      float val;
      if (j == 0)          val = vsink[c];
      else if (j <= T_SEQ) val = qkv[(size_t)(j - 1) * 3072 + (c >> 7) * 768 + 640 + (c & 127)];
      else                 val = 0.f;
      tl[c * 33 + jj] = f2bf(val);
    }
    __syncthreads();
#pragma unroll 4
    for (int st = 0; st < 32; ++st) {
      int id = st * 256 + tid;            // 8,192 = 512 rows x 16 jp-pairs
      int row = id >> 4, jp = (id & 15) << 1;
      ushort2 w = { tl[row * 33 + jp], tl[row * 33 + jp + 1] };
      *(ushort2*)(vtb + (size_t)row * JP + j0 + jp) = w;
    }
  }
}

// ---------------------------------------------------------------------------
// MFMA flash attention, j-split x2: 8 waves = 4 heads x 2 key-range halves.
// Each half runs the online-softmax loop on its chunk sub-range; halves merge
// lane-wise through LDS (exact rescale).  Output pre-split for gemm_sp.
// ---------------------------------------------------------------------------
__global__ __launch_bounds__(512) void attn_mfma_bf16(const unsigned short* __restrict__ qb,
                                                      const unsigned short* __restrict__ kb,
                                                      const unsigned short* __restrict__ vtb,
                                                      uint4* __restrict__ ofs) {
  __shared__ float sm_m[4][64], sm_l[4][64];
  __shared__ float sm_acc[4][64][32];

  const int bid  = blockIdx.x;
  const int tile = bid >> 2;
  const int g    = bid & 3;
  const int wv   = threadIdx.x >> 6;
  const int half = wv >> 2;               // 0 = lower j-range, 1 = upper
  const int hq   = wv & 3;
  const int h    = g * 4 + hq;
  const int lane = threadIdx.x & 63;
  const int lo   = lane & 15;
  const int hi   = lane >> 4;
  const int t0   = tile << 4;
  const int t    = t0 + lo;

  short8 qfrag[4];
  {
    const unsigned short* qp = qb + (size_t)t * 2048 + h * 128 + (hi << 3);
#pragma unroll
    for (int d0 = 0; d0 < 4; ++d0) qfrag[d0] = *(const short8*)(qp + d0 * 32);
  }

  f32x4 acc[8];
  const f32x4 z4 = {0.f, 0.f, 0.f, 0.f};
#pragma unroll
  for (int dt = 0; dt < 8; ++dt) acc[dt] = z4;

  float m = -1e4f, l = 0.f;               // per-lane partial stats

  int jlo = t0 - 1022; if (jlo < 0) jlo = 0;
  const int jb0  = jlo & ~31;
  const int jmax = t0 + 16;
  const int nch  = ((jmax - jb0) >> 5) + 1;
  const int nlo  = (nch + 1) >> 1;
  const int cb   = half ? nlo : 0;
  const int ce   = half ? nch : nlo;
  const int jrowA = ((lo >> 2) << 3) + (lo & 3);

  for (int ci = cb; ci < ce; ++ci) {
    const int jb = jb0 + (ci << 5);
    const unsigned short* kbase = kb + (size_t)(jb + jrowA) * 512 + g * 128 + (hi << 3);
    f32x4 sa = z4, sb = z4;
#pragma unroll
    for (int d0 = 0; d0 < 4; ++d0) {
      short8 ka = *(const short8*)(kbase + d0 * 32);
      short8 kB = *(const short8*)(kbase + 4 * 512 + d0 * 32);
      sa = __builtin_amdgcn_mfma_f32_16x16x32_bf16(ka, qfrag[d0], sa, 0, 0, 0);
      sb = __builtin_amdgcn_mfma_f32_16x16x32_bf16(kB, qfrag[d0], sb, 0, 0, 0);
    }

    float z[8];
    const int jbase = jb + (hi << 3);
    const bool interior = (jb >= t0 - 1007) && (jb <= t0 - 30);
    if (interior) {
#pragma unroll
      for (int r = 0; r < 4; ++r) { z[r] = sa[r] * SL_F; z[r + 4] = sb[r] * SL_F; }
    } else {
#pragma unroll
      for (int r = 0; r < 8; ++r) {
        float sv = (r < 4) ? sa[r] : sb[r - 4];
        int j = jbase + r;
        bool valid = (j <= t + 1) && (j >= t - 1022);
        z[r] = valid ? sv * SL_F : -1e30f;
      }
    }

    float lmax = fmaxf(fmaxf(fmaxf(z[0], z[1]), fmaxf(z[2], z[3])),
                       fmaxf(fmaxf(z[4], z[5]), fmaxf(z[6], z[7])));
    if (!__all(lmax <= m + THR_L2)) {
      float cm = lmax;
      cm = fmaxf(cm, __shfl_xor(cm, 16, 64));
      cm = fmaxf(cm, __shfl_xor(cm, 32, 64));
      float mn = fmaxf(m, cm);
      float a  = exp2f(m - mn);
      l *= a;
#pragma unroll
      for (int dt = 0; dt < 8; ++dt) acc[dt] *= a;
      m = mn;
    }

    float p[8];
#pragma unroll
    for (int r = 0; r < 8; ++r) { p[r] = exp2f(z[r] - m); l += p[r]; }

    short8 pfrag;
#pragma unroll
    for (int e = 0; e < 8; ++e) pfrag[e] = (short)f2bf(p[e]);

    const unsigned short* vbase = vtb + (size_t)(g * 128 + lo) * JP + jb + (hi << 3);
#pragma unroll
    for (int dt = 0; dt < 8; ++dt) {
      short8 vf = *(const short8*)(vbase + (size_t)dt * 16 * JP);
      acc[dt] = __builtin_amdgcn_mfma_f32_16x16x32_bf16(vf, pfrag, acc[dt], 0, 0, 0);
    }
  }

  // ---- merge halves through LDS (exact)
  if (half == 1) {
    sm_m[hq][lane] = m;
    sm_l[hq][lane] = l;
#pragma unroll
    for (int dt = 0; dt < 8; ++dt)
      *(f32x4*)&sm_acc[hq][lane][dt << 2] = acc[dt];
  }
  __syncthreads();
  if (half == 1) return;

  {
    float m2 = sm_m[hq][lane], l2 = sm_l[hq][lane];
    float mN = fmaxf(m, m2);
    float a1 = exp2f(m - mN), a2 = exp2f(m2 - mN);
    l = l * a1 + l2 * a2;
#pragma unroll
    for (int dt = 0; dt < 8; ++dt) {
      f32x4 acc2 = *(const f32x4*)&sm_acc[hq][lane][dt << 2];
      acc[dt] = acc[dt] * a1 + acc2 * a2;
    }
  }

  float lt = l;
  lt += __shfl_xor(lt, 16, 64);
  lt += __shfl_xor(lt, 32, 64);
  const float inv = 1.f / lt;

  // epilogue: write pre-split interleaved groups (hi trunc / lo RNE)
  const size_t elem = (size_t)t * 2048 + h * 128 + (hi << 2);
#pragma unroll
  for (int dt = 0; dt < 8; ++dt) {
    f32x4 o4 = acc[dt] * inv;
    unsigned int h0 = __float_as_uint(o4[0]) & 0xffff0000u;
    unsigned int h1 = __float_as_uint(o4[1]) & 0xffff0000u;
    unsigned int h2 = __float_as_uint(o4[2]) & 0xffff0000u;
    unsigned int h3 = __float_as_uint(o4[3]) & 0xffff0000u;
    unsigned int l0 = f2bf(o4[0] - __uint_as_float(h0));
    unsigned int l1 = f2bf(o4[1] - __uint_as_float(h1));
    unsigned int l2 = f2bf(o4[2] - __uint_as_float(h2));
    unsigned int l3 = f2bf(o4[3] - __uint_as_float(h3));
    uint4 pk;
    pk.x = (h0 >> 16) | (h1 & 0xffff0000u);
    pk.y = (h2 >> 16) | (h3 & 0xffff0000u);
    pk.z = l0 | (l1 << 16);
    pk.w = l2 | (l3 << 16);
    ofs[(elem >> 2) + dt * 4] = pk;
  }
}

extern "C" void kernel_launch(void* const* d_in, const int* in_sizes, int n_in,
                              void* d_out, int out_size, void* d_ws, size_t ws_size,
                              hipStream_t stream) {
  const float* x     = (const float*)d_in[0];   // (2048, 2048) f32
  const float* cosb  = (const float*)d_in[1];   // (2048, 64)   f32
  const float* sinb  = (const float*)d_in[2];   // (2048, 64)   f32
  const float* Wa    = (const float*)d_in[3];   // (3072, 2048) f32
  const float* Wp    = (const float*)d_in[4];   // (2048, 2048) f32
  const float* ksink = (const float*)d_in[5];   // (512,)       f32
  const float* vsink = (const float*)d_in[6];   // (512,)       f32
  float* y = (float*)d_out;                     // (2048, 2048) f32

  // Workspace aliasing plan (peak 67,108,864 B; stream-serial stages):
  //  [0,        25165824): qkv f32            (stages 2-3)
  //  [0,        16777216): wps (Wp split)     (stage 4+; qkv dead after rope)
  //  [25165824, 50331648): was (Wa split)     (stages 1-2)
  //  [25165824, 41943040): ofs (attn out)     (stage 5+; was dead after GEMM1)
  //  [50331648, 67108864): xs  (x split)      (stages 1-2)
  //  [50331648, 62980096): qb/kb/vtb          (stage 3+; xs dead after GEMM1)
  char* ws = (char*)d_ws;
  float*          qkv = (float*)ws;
  uint4*          wps = (uint4*)ws;
  uint4*          was = (uint4*)(ws + 25165824);
  uint4*          ofs = (uint4*)(ws + 25165824);
  uint4*          xs  = (uint4*)(ws + 50331648);
  unsigned short* qb  = (unsigned short*)(ws + 50331648);
  unsigned short* kbb = (unsigned short*)(ws + 58720256);
  unsigned short* vtb = (unsigned short*)(ws + 60850176);

  // 1. pre-split x and Wa (interleaved hi/lo)
  split_pack<<<10240, 256, 0, stream>>>((const float4*)x, xs, 1048576,
                                        (const float4*)Wa, was, 1572864);
  // 2. qkv = x @ Wa^T  (split MFMA, pre-split operands)
  gemm_sp<<<dim3(48, 16), 256, 0, stream>>>(xs, was, qkv, 2048, 3072, 2048);
  // 3. RoPE + operand assembly (coalesced; LDS-transposed V)
  rope2<<<RB_Q + RB_K + RB_KE + RB_V, 256, 0, stream>>>(qkv, cosb, sinb, ksink, vsink,
                                                        qb, kbb, vtb);
  // 4. pre-split Wp (into dead qkv region)
  split_pack<<<4096, 256, 0, stream>>>((const float4*)Wp, wps, 1048576,
                                       (const float4*)Wp, wps, 0);
  // 5. MFMA flash attention (j-split x2, writes pre-split output)
  attn_mfma_bf16<<<512, 512, 0, stream>>>(qb, kbb, vtb, ofs);
  // 6. y = o @ Wp^T
  gemm_sp<<<dim3(32, 16), 256, 0, stream>>>(ofs, wps, y, 2048, 2048, 2048);
}

// Round 6
// 325.320 us; speedup vs baseline: 5.4478x; 1.1716x over previous
//
#include <hip/hip_runtime.h>

#define T_SEQ  2048
#define TK_SEQ 2049
#define JP     2080                       // padded key length (zeroed pads)
#define SCALE_F 0.08838834764831845f
#define SL_F    0.12751744f               // SCALE * log2(e)
#define THR_L2  11.0f                     // defer-max threshold (log2 domain)

typedef __attribute__((ext_vector_type(8))) short short8;
typedef __attribute__((ext_vector_type(4))) float f32x4;

__device__ __forceinline__ unsigned short f2bf(float f) {
  unsigned int u = __float_as_uint(f);
  u += 0x7fff + ((u >> 16) & 1);          // round-to-nearest-even
  return (unsigned short)(u >> 16);
}

// ---------------------------------------------------------------------------
// split_pack: f32 -> interleaved split groups of 4: {4x bf16 hi (trunc),
// 4x bf16 lo (RNE of residual)} = 16 B per 4 floats.  Two ranges per launch.
// ---------------------------------------------------------------------------
__global__ __launch_bounds__(256) void split_pack(const float4* __restrict__ s0,
                                                  uint4* __restrict__ d0, int n0,
                                                  const float4* __restrict__ s1,
                                                  uint4* __restrict__ d1, int n1) {
  int i = blockIdx.x * 256 + threadIdx.x;
  const float4* s; uint4* d; int k;
  if (i < n0) { s = s0; d = d0; k = i; }
  else { k = i - n0; if (k >= n1) return; s = s1; d = d1; }
  float4 f = s[k];
  unsigned int h0 = __float_as_uint(f.x) & 0xffff0000u;
  unsigned int h1 = __float_as_uint(f.y) & 0xffff0000u;
  unsigned int h2 = __float_as_uint(f.z) & 0xffff0000u;
  unsigned int h3 = __float_as_uint(f.w) & 0xffff0000u;
  unsigned int l0 = f2bf(f.x - __uint_as_float(h0));
  unsigned int l1 = f2bf(f.y - __uint_as_float(h1));
  unsigned int l2 = f2bf(f.z - __uint_as_float(h2));
  unsigned int l3 = f2bf(f.w - __uint_as_float(h3));
  uint4 o;
  o.x = (h0 >> 16) | (h1 & 0xffff0000u);
  o.y = (h2 >> 16) | (h3 & 0xffff0000u);
  o.z = l0 | (l1 << 16);
  o.w = l2 | (l3 << 16);
  d[k] = o;
}

// ---------------------------------------------------------------------------
// Split-f32 MFMA GEMM, pre-split operands.  (unchanged this round)
// ---------------------------------------------------------------------------
#define LDK 56

__global__ __launch_bounds__(256, 3) void gemm_sp(const uint4* __restrict__ As,
                                                  const uint4* __restrict__ Bs,
                                                  float* __restrict__ C,
                                                  int M, int N, int K) {
  __shared__ unsigned short Ah[128 * LDK], Al[128 * LDK];
  __shared__ unsigned short Bh[64 * LDK],  Bl[64 * LDK];

  const int tid  = threadIdx.x;
  const int lane = tid & 63;
  const int wid  = tid >> 6;
  const int wm   = (wid >> 1) << 6;       // 0 / 64
  const int wn   = (wid & 1) << 5;        // 0 / 32
  const int lo16 = lane & 15;
  const int hi4  = lane >> 4;
  const int m0   = blockIdx.y << 7;
  const int n0   = blockIdx.x << 6;
  const int Kg   = K >> 2;                // groups of 4 per row

  const uint4* pa[4];
  const uint4* pb[2];
  int waofs[4], wbofs[2];
#pragma unroll
  for (int v = 0; v < 4; ++v) {
    int id = (v << 8) + tid;
    int r  = id >> 3;
    int kc = (id & 7) << 2;
    pa[v]    = As + (size_t)(m0 + r) * Kg + (kc >> 2);
    waofs[v] = r * LDK + kc;
  }
#pragma unroll
  for (int v = 0; v < 2; ++v) {
    int id = (v << 8) + tid;
    int r  = id >> 3;
    int kc = (id & 7) << 2;
    pb[v]    = Bs + (size_t)(n0 + r) * Kg + (kc >> 2);
    wbofs[v] = r * LDK + kc;
  }

  int ra[4], rb[2];
#pragma unroll
  for (int i = 0; i < 4; ++i) ra[i] = (wm + i * 16 + lo16) * LDK + (hi4 << 3);
#pragma unroll
  for (int j = 0; j < 2; ++j) rb[j] = (wn + j * 16 + lo16) * LDK + (hi4 << 3);

  f32x4 acc[4][2];
  const f32x4 z4 = {0.f, 0.f, 0.f, 0.f};
#pragma unroll
  for (int i = 0; i < 4; ++i)
#pragma unroll
    for (int j = 0; j < 2; ++j) acc[i][j] = z4;

  uint4 av[4], bv[2];
#pragma unroll
  for (int v = 0; v < 4; ++v) av[v] = pa[v][0];
#pragma unroll
  for (int v = 0; v < 2; ++v) bv[v] = pb[v][0];

  for (int k0 = 0; k0 < K; k0 += 32) {
    __syncthreads();
#pragma unroll
    for (int v = 0; v < 4; ++v) {
      uint2 ah = {av[v].x, av[v].y}, al = {av[v].z, av[v].w};
      *(uint2*)&Ah[waofs[v]] = ah;
      *(uint2*)&Al[waofs[v]] = al;
    }
#pragma unroll
    for (int v = 0; v < 2; ++v) {
      uint2 bh = {bv[v].x, bv[v].y}, bl = {bv[v].z, bv[v].w};
      *(uint2*)&Bh[wbofs[v]] = bh;
      *(uint2*)&Bl[wbofs[v]] = bl;
    }
    __syncthreads();
    if (k0 + 32 < K) {
      int kg = (k0 + 32) >> 2;
#pragma unroll
      for (int v = 0; v < 4; ++v) av[v] = pa[v][kg];
#pragma unroll
      for (int v = 0; v < 2; ++v) bv[v] = pb[v][kg];
    }
    short8 fah[4], fal[4], fbh[2], fbl[2];
#pragma unroll
    for (int i = 0; i < 4; ++i) {
      fah[i] = *(const short8*)&Ah[ra[i]];
      fal[i] = *(const short8*)&Al[ra[i]];
    }
#pragma unroll
    for (int j = 0; j < 2; ++j) {
      fbh[j] = *(const short8*)&Bh[rb[j]];
      fbl[j] = *(const short8*)&Bl[rb[j]];
    }
#pragma unroll
    for (int i = 0; i < 4; ++i)
#pragma unroll
      for (int j = 0; j < 2; ++j) {
        acc[i][j] = __builtin_amdgcn_mfma_f32_16x16x32_bf16(fah[i], fbh[j], acc[i][j], 0, 0, 0);
        acc[i][j] = __builtin_amdgcn_mfma_f32_16x16x32_bf16(fal[i], fbh[j], acc[i][j], 0, 0, 0);
        acc[i][j] = __builtin_amdgcn_mfma_f32_16x16x32_bf16(fah[i], fbl[j], acc[i][j], 0, 0, 0);
      }
  }

#pragma unroll
  for (int i = 0; i < 4; ++i) {
    const int row = m0 + wm + i * 16 + (hi4 << 2);
#pragma unroll
    for (int j = 0; j < 2; ++j) {
      float* cp = C + (size_t)row * N + n0 + wn + j * 16 + lo16;
      cp[0]            = acc[i][j][0];
      cp[(size_t)N]    = acc[i][j][1];
      cp[(size_t)2*N]  = acc[i][j][2];
      cp[(size_t)3*N]  = acc[i][j][3];
    }
  }
}

// ---------------------------------------------------------------------------
// rope2: RoPE + bf16 operand assembly, all sections coalesced.  (unchanged)
// ---------------------------------------------------------------------------
#define RB_Q  4096
#define RB_K  1024
#define RB_KE 64
#define RB_V  65

__global__ __launch_bounds__(256) void rope2(const float* __restrict__ qkv,
                                             const float* __restrict__ cosb,
                                             const float* __restrict__ sinb,
                                             const float* __restrict__ ksink,
                                             const float* __restrict__ vsink,
                                             unsigned short* __restrict__ qb,
                                             unsigned short* __restrict__ kb,
                                             unsigned short* __restrict__ vtb) {
  __shared__ unsigned short tl[512 * 33];
  const int bid = blockIdx.x, tid = threadIdx.x;
  if (bid < RB_Q) {
    int idx = bid * 256 + tid;            // 1,048,576: (t, h, dp/2)
    int t = idx >> 9, rem = idx & 511;
    int h = rem >> 5, dp = (rem & 31) << 1;
    int g = h >> 2, qi = h & 3;
    const float* src = qkv + (size_t)t * 3072 + g * 768 + qi * 128;
    float2 x1 = *(const float2*)(src + dp);
    float2 x2 = *(const float2*)(src + 64 + dp);
    float2 c  = *(const float2*)(cosb + t * 64 + dp);
    float2 s  = *(const float2*)(sinb + t * 64 + dp);
    ushort2 o1 = { f2bf(x1.x * c.x - x2.x * s.x), f2bf(x1.y * c.y - x2.y * s.y) };
    ushort2 o2 = { f2bf(x1.x * s.x + x2.x * c.x), f2bf(x1.y * s.y + x2.y * c.y) };
    *(ushort2*)(qb + (size_t)t * 2048 + h * 128 + dp)      = o1;
    *(ushort2*)(qb + (size_t)t * 2048 + h * 128 + 64 + dp) = o2;
  } else if (bid < RB_Q + RB_K) {
    int idx = (bid - RB_Q) * 256 + tid;   // 262,144: (t, g, dp/2)
    int t = idx >> 7, rem = idx & 127;
    int g = rem >> 5, dp = (rem & 31) << 1;
    const float* src = qkv + (size_t)t * 3072 + g * 768 + 512;
    float2 x1 = *(const float2*)(src + dp);
    float2 x2 = *(const float2*)(src + 64 + dp);
    float2 c  = *(const float2*)(cosb + t * 64 + dp);
    float2 s  = *(const float2*)(sinb + t * 64 + dp);
    ushort2 o1 = { f2bf(x1.x * c.x - x2.x * s.x), f2bf(x1.y * c.y - x2.y * s.y) };
    ushort2 o2 = { f2bf(x1.x * s.x + x2.x * c.x), f2bf(x1.y * s.y + x2.y * c.y) };
    size_t base = (size_t)(t + 1) * 512 + g * 128 + dp;
    *(ushort2*)(kb + base)      = o1;
    *(ushort2*)(kb + base + 64) = o2;
  } else if (bid < RB_Q + RB_K + RB_KE) {
    int idx = (bid - RB_Q - RB_K) * 256 + tid;   // 16,384: sink + pads
    int jj = idx >> 9, c = idx & 511;
    if (jj == 0) kb[c] = f2bf(ksink[c]);
    else         kb[(size_t)(2048 + jj) * 512 + c] = 0;
  } else {
    int b  = bid - RB_Q - RB_K - RB_KE;   // 0..64, j-tile of 32
    int j0 = b << 5;
#pragma unroll 4
    for (int st = 0; st < 64; ++st) {
      int id = st * 256 + tid;            // 16,384 = 32 j x 512 gd
      int jj = id >> 9, c = id & 511;
      int j = j0 + jj;
      float val;
      if (j == 0)          val = vsink[c];
      else if (j <= T_SEQ) val = qkv[(size_t)(j - 1) * 3072 + (c >> 7) * 768 + 640 + (c & 127)];
      else                 val = 0.f;
      tl[c * 33 + jj] = f2bf(val);
    }
    __syncthreads();
#pragma unroll 4
    for (int st = 0; st < 32; ++st) {
      int id = st * 256 + tid;            // 8,192 = 512 rows x 16 jp-pairs
      int row = id >> 4, jp = (id & 15) << 1;
      ushort2 w = { tl[row * 33 + jp], tl[row * 33 + jp + 1] };
      *(ushort2*)(vtb + (size_t)row * JP + j0 + jp) = w;
    }
  }
}

// ---------------------------------------------------------------------------
// MFMA flash attention with per-block LDS K/V staging (double-buffered).
// Block = 8 waves = 4 heads x 2 q-subtiles (32 q-rows), ONE group, ONE shared
// j-window: K/V staged ONCE per chunk per block -> 8x less cache traffic.
// K placed at permuted LDS row phi(j)=((j&7)<<2)|(j>>3), stride 136 elems;
// V stride 40: both at the b128 bank floor.  Inner math unchanged (verified).
// ---------------------------------------------------------------------------
#define KSTR 136
#define VSTR 40

__global__ __launch_bounds__(512) void attn_mfma_bf16(const unsigned short* __restrict__ qb,
                                                      const unsigned short* __restrict__ kb,
                                                      const unsigned short* __restrict__ vtb,
                                                      uint4* __restrict__ ofs) {
  __shared__ unsigned short Kl[2][32 * KSTR];   // 2 x 8704 B
  __shared__ unsigned short Vl[2][128 * VSTR];  // 2 x 10240 B

  const int bid  = blockIdx.x;
  const int tile = bid >> 2;              // 0..63 (32-row q-tiles)
  const int g    = bid & 3;
  const int t0b  = tile << 5;
  const int tid  = threadIdx.x;
  const int wv   = tid >> 6;
  const int hq   = wv & 3;
  const int sub  = wv >> 2;               // q-subtile within block
  const int h    = g * 4 + hq;
  const int lane = tid & 63;
  const int lo   = lane & 15;
  const int hi   = lane >> 4;
  const int t0w  = t0b + (sub << 4);
  const int t    = t0w + lo;              // this lane's q row

  // staging map: K: thread -> (local row sj, col sc); V: (d-row svd, col svj)
  const int sj   = tid >> 4;              // 0..31
  const int sc   = (tid & 15) << 3;       // 0,8,...,120
  const int kphi = ((((sj & 7) << 2) | (sj >> 3))) * KSTR + sc;
  const int svd  = tid >> 2;              // 0..127
  const int svj  = (tid & 3) << 3;        // 0,8,16,24
  const int vdst = svd * VSTR + svj;
  const unsigned short* ksrc = kb  + (size_t)sj * 512 + g * 128 + sc;
  const unsigned short* vsrc = vtb + (size_t)(g * 128 + svd) * JP + svj;

  // Q fragment (B operand of QK): lane holds q[t][d0*32 + 8*hi + e]
  short8 qfrag[4];
  {
    const unsigned short* qp = qb + (size_t)t * 2048 + h * 128 + (hi << 3);
#pragma unroll
    for (int d0 = 0; d0 < 4; ++d0) qfrag[d0] = *(const short8*)(qp + d0 * 32);
  }

  f32x4 acc[8];
  const f32x4 z4 = {0.f, 0.f, 0.f, 0.f};
#pragma unroll
  for (int dt = 0; dt < 8; ++dt) acc[dt] = z4;

  float m = -1e4f, l = 0.f;               // per-lane partial stats

  int jlo = t0b - 1022; if (jlo < 0) jlo = 0;
  const int jb0  = jlo & ~31;
  const int jmax = t0b + 32;              // largest valid j = (t0b+31)+1
  const int nch  = ((jmax - jb0) >> 5) + 1;

  // LDS fragment read offsets (K rows permuted: tile A -> phi in [0,16),
  // tile B (= row+4) -> phi+16)
  const int klA = (((lo & 3) << 2) | (lo >> 2)) * KSTR + (hi << 3);

  // prologue: stage chunk 0
  uint4 kreg = *(const uint4*)(ksrc + (size_t)jb0 * 512);
  uint4 vreg = *(const uint4*)(vsrc + jb0);
  *(uint4*)&Kl[0][kphi] = kreg;
  *(uint4*)&Vl[0][vdst] = vreg;
  __syncthreads();

  int bsel = 0;
  for (int ci = 0; ci < nch; ++ci) {
    const int jb = jb0 + (ci << 5);
    const bool more = (ci + 1 < nch);
    if (more) {                            // issue next-chunk loads early
      const int jn = jb + 32;
      kreg = *(const uint4*)(ksrc + (size_t)jn * 512);
      vreg = *(const uint4*)(vsrc + jn);
    }

    // ---- QK^T: two 16x16 S^T tiles over K=128 (4 d-chunks), from LDS
    const unsigned short* Kb = &Kl[bsel][0];
    f32x4 sa = z4, sb = z4;
#pragma unroll
    for (int d0 = 0; d0 < 4; ++d0) {
      short8 ka  = *(const short8*)(Kb + klA + d0 * 32);
      short8 kB2 = *(const short8*)(Kb + klA + 16 * KSTR + d0 * 32);
      sa = __builtin_amdgcn_mfma_f32_16x16x32_bf16(ka,  qfrag[d0], sa, 0, 0, 0);
      sb = __builtin_amdgcn_mfma_f32_16x16x32_bf16(kB2, qfrag[d0], sb, 0, 0, 0);
    }

    float z[8];
    const int jbase = jb + (hi << 3);
    const bool interior = (jb >= t0w - 1007) && (jb <= t0w - 30);
    if (interior) {
#pragma unroll
      for (int r = 0; r < 4; ++r) { z[r] = sa[r] * SL_F; z[r + 4] = sb[r] * SL_F; }
    } else {
#pragma unroll
      for (int r = 0; r < 8; ++r) {
        float sv = (r < 4) ? sa[r] : sb[r - 4];
        int j = jbase + r;
        bool valid = (j <= t + 1) && (j >= t - 1022);
        z[r] = valid ? sv * SL_F : -1e30f;
      }
    }

    float lmax = fmaxf(fmaxf(fmaxf(z[0], z[1]), fmaxf(z[2], z[3])),
                       fmaxf(fmaxf(z[4], z[5]), fmaxf(z[6], z[7])));
    if (!__all(lmax <= m + THR_L2)) {
      float cm = lmax;
      cm = fmaxf(cm, __shfl_xor(cm, 16, 64));
      cm = fmaxf(cm, __shfl_xor(cm, 32, 64));
      float mn = fmaxf(m, cm);
      float a  = exp2f(m - mn);
      l *= a;
#pragma unroll
      for (int dt = 0; dt < 8; ++dt) acc[dt] *= a;
      m = mn;
    }

    float p[8];
#pragma unroll
    for (int r = 0; r < 8; ++r) { p[r] = exp2f(z[r] - m); l += p[r]; }

    short8 pfrag;
#pragma unroll
    for (int e = 0; e < 8; ++e) pfrag[e] = (short)f2bf(p[e]);

    // ---- PV: O^T += V^T * P^T  (8 d-tiles of 16), from LDS
    const unsigned short* Vb = &Vl[bsel][0];
#pragma unroll
    for (int dt = 0; dt < 8; ++dt) {
      short8 vf = *(const short8*)(Vb + (dt * 16 + lo) * VSTR + (hi << 3));
      acc[dt] = __builtin_amdgcn_mfma_f32_16x16x32_bf16(vf, pfrag, acc[dt], 0, 0, 0);
    }

    if (more) {                            // write next chunk, flip buffers
      *(uint4*)&Kl[bsel ^ 1][kphi] = kreg;
      *(uint4*)&Vl[bsel ^ 1][vdst] = vreg;
      __syncthreads();
      bsel ^= 1;
    }
  }

  float lt = l;
  lt += __shfl_xor(lt, 16, 64);
  lt += __shfl_xor(lt, 32, 64);
  const float inv = 1.f / lt;

  // epilogue: write pre-split interleaved groups (hi trunc / lo RNE)
  const size_t elem = (size_t)t * 2048 + h * 128 + (hi << 2);
#pragma unroll
  for (int dt = 0; dt < 8; ++dt) {
    f32x4 o4 = acc[dt] * inv;
    unsigned int h0 = __float_as_uint(o4[0]) & 0xffff0000u;
    unsigned int h1 = __float_as_uint(o4[1]) & 0xffff0000u;
    unsigned int h2 = __float_as_uint(o4[2]) & 0xffff0000u;
    unsigned int h3 = __float_as_uint(o4[3]) & 0xffff0000u;
    unsigned int l0 = f2bf(o4[0] - __uint_as_float(h0));
    unsigned int l1 = f2bf(o4[1] - __uint_as_float(h1));
    unsigned int l2 = f2bf(o4[2] - __uint_as_float(h2));
    unsigned int l3 = f2bf(o4[3] - __uint_as_float(h3));
    uint4 pk;
    pk.x = (h0 >> 16) | (h1 & 0xffff0000u);
    pk.y = (h2 >> 16) | (h3 & 0xffff0000u);
    pk.z = l0 | (l1 << 16);
    pk.w = l2 | (l3 << 16);
    ofs[(elem >> 2) + dt * 4] = pk;
  }
}

extern "C" void kernel_launch(void* const* d_in, const int* in_sizes, int n_in,
                              void* d_out, int out_size, void* d_ws, size_t ws_size,
                              hipStream_t stream) {
  const float* x     = (const float*)d_in[0];   // (2048, 2048) f32
  const float* cosb  = (const float*)d_in[1];   // (2048, 64)   f32
  const float* sinb  = (const float*)d_in[2];   // (2048, 64)   f32
  const float* Wa    = (const float*)d_in[3];   // (3072, 2048) f32
  const float* Wp    = (const float*)d_in[4];   // (2048, 2048) f32
  const float* ksink = (const float*)d_in[5];   // (512,)       f32
  const float* vsink = (const float*)d_in[6];   // (512,)       f32
  float* y = (float*)d_out;                     // (2048, 2048) f32

  // Workspace aliasing plan (peak 67,108,864 B; stream-serial stages):
  //  [0,        25165824): qkv f32            (stages 2-3)
  //  [0,        16777216): wps (Wp split)     (stage 4+; qkv dead after rope)
  //  [25165824, 50331648): was (Wa split)     (stages 1-2)
  //  [25165824, 41943040): ofs (attn out)     (stage 5+; was dead after GEMM1)
  //  [50331648, 67108864): xs  (x split)      (stages 1-2)
  //  [50331648, 62980096): qb/kb/vtb          (stage 3+; xs dead after GEMM1)
  char* ws = (char*)d_ws;
  float*          qkv = (float*)ws;
  uint4*          wps = (uint4*)ws;
  uint4*          was = (uint4*)(ws + 25165824);
  uint4*          ofs = (uint4*)(ws + 25165824);
  uint4*          xs  = (uint4*)(ws + 50331648);
  unsigned short* qb  = (unsigned short*)(ws + 50331648);
  unsigned short* kbb = (unsigned short*)(ws + 58720256);
  unsigned short* vtb = (unsigned short*)(ws + 60850176);

  // 1. pre-split x and Wa (interleaved hi/lo)
  split_pack<<<10240, 256, 0, stream>>>((const float4*)x, xs, 1048576,
                                        (const float4*)Wa, was, 1572864);
  // 2. qkv = x @ Wa^T  (split MFMA, pre-split operands)
  gemm_sp<<<dim3(48, 16), 256, 0, stream>>>(xs, was, qkv, 2048, 3072, 2048);
  // 3. RoPE + operand assembly (coalesced; LDS-transposed V)
  rope2<<<RB_Q + RB_K + RB_KE + RB_V, 256, 0, stream>>>(qkv, cosb, sinb, ksink, vsink,
                                                        qb, kbb, vtb);
  // 4. pre-split Wp (into dead qkv region)
  split_pack<<<4096, 256, 0, stream>>>((const float4*)Wp, wps, 1048576,
                                       (const float4*)Wp, wps, 0);
  // 5. MFMA flash attention (LDS-staged K/V, writes pre-split output)
  attn_mfma_bf16<<<256, 512, 0, stream>>>(qb, kbb, vtb, ofs);
  // 6. y = o @ Wp^T
  gemm_sp<<<dim3(32, 16), 256, 0, stream>>>(ofs, wps, y, 2048, 2048, 2048);
}